// Round 6
// baseline (323.681 us; speedup 1.0000x reference)
//
#include <hip/hip_runtime.h>
#include <math.h>

typedef _Float16 half8 __attribute__((ext_vector_type(8)));
typedef float f32x4 __attribute__((ext_vector_type(4)));
typedef float f32x16 __attribute__((ext_vector_type(16)));

constexpr int kNFFT    = 1024;
constexpr int kHop     = 320;
constexpr int kMels    = 128;
constexpr int kFrames  = 1000;
constexpr int kBatch   = 32;
constexpr int kXLen    = 320000;
constexpr int kYLen    = kXLen - 1;          // 319999
constexpr int kYPad    = 328704;             // >= 1023*320+1024, mult of 2048
constexpr int kYOff    = 512;                // center-pad offset
constexpr float kPre   = 0.97f;
constexpr int kPStride = 544;                // power row stride (bins padded 513->544)

// ws layout (offsets in _Float16 elements)
constexpr size_t kYLvl     = (size_t)kBatch * kYPad;            // halfs per level
constexpr size_t kFragLvl  = 32ull * 64 * 64 * 8;               // 1,048,576 halfs per level
constexpr size_t kFragOff  = 2 * kYLvl;                         // 21,037,056
constexpr size_t kMelFrOff = kFragOff + 2 * kFragLvl;           // 23,134,208
constexpr size_t kMelFrSz  = 8ull * 17 * 64 * 8;                // 69,632 halfs
constexpr size_t kPowOff   = kMelFrOff + kMelFrSz;              // 23,203,840

// fused prep grid partition
constexpr int kYJobBlks   = (kYPad / 8 + 255) / 256;            // 161
constexpr int kYJobTotal  = kYJobBlks * kBatch;                 // 5152
constexpr int kFragBlks   = 131072 / 256;                       // 512
constexpr int kMelBlks    = (8 * 17 * 64) / 256;                // 34
constexpr int kPrepGrid   = kYJobTotal + kFragBlks + kMelBlks;  // 5698

// ---- fused prep: y split / fourier frags / mel frags ----
__global__ void prep_all(const float* __restrict__ x, const float* __restrict__ basis,
                         const float* __restrict__ melb, _Float16* __restrict__ ws) {
    _Float16* ypad  = ws;
    _Float16* fr    = ws + kFragOff;
    _Float16* melfr = ws + kMelFrOff;
    const int bid = blockIdx.x;
    const int tid = threadIdx.x;

    if (bid < kYJobTotal) {
        // --- pre-emphasis + center pad, 2-level f16 split, 8 elems/thread ---
        int b = bid / kYJobBlks;
        int blk = bid - b * kYJobBlks;
        int e0 = (blk * 256 + tid) * 8;
        if (e0 >= kYPad) return;
        const float* xb = x + (size_t)b * kXLen;
        int yi = e0 - kYOff;
        float v[8];
        if (yi >= 0 && yi <= kXLen - 9) {
            float4 A = *(const float4*)(xb + yi);
            float4 B = *(const float4*)(xb + yi + 4);
            float C = xb[yi + 8];
            v[0] = A.y - kPre * A.x;  v[1] = A.z - kPre * A.y;
            v[2] = A.w - kPre * A.z;  v[3] = B.x - kPre * A.w;
            v[4] = B.y - kPre * B.x;  v[5] = B.z - kPre * B.y;
            v[6] = B.w - kPre * B.z;  v[7] = C   - kPre * B.w;
        } else {
            #pragma unroll
            for (int j = 0; j < 8; ++j) {
                int g = yi + j;
                v[j] = (g >= 0 && g < kYLen) ? xb[g + 1] - kPre * xb[g] : 0.0f;
            }
        }
        half8 hv, mv;
        #pragma unroll
        for (int j = 0; j < 8; ++j) {
            _Float16 h = (_Float16)v[j];
            hv[j] = h;
            mv[j] = (_Float16)(v[j] - (float)h);
        }
        size_t idx = (size_t)b * kYPad + e0;
        *(half8*)(ypad + idx) = hv;
        *(half8*)(ypad + idx + kYLvl) = mv;
    } else if (bid < kYJobTotal + kFragBlks) {
        // --- fourier basis -> 32x32x16 A-fragments, 2-level f16 split ---
        // packed rows: 0..512 cos bins 0..512; 513..1023 sin bins 1..511 (orig r+1)
        // frag[lv][G][kh][lane][j]: A[m=32G+(lane&31)][k=16kh+(lane>>5)*8+j]
        int id = (bid - kYJobTotal) * 256 + tid;   // < 131072
        int L  = id & 63;
        int kh = (id >> 6) & 63;
        int G  = id >> 12;                          // 0..31
        int r  = 32 * G + (L & 31);
        int orig = (r <= 512) ? r : r + 1;
        const float* src = basis + (size_t)orig * kNFFT + 16 * kh + (L >> 5) * 8;
        _Float16* dst = fr + (size_t)id * 8;        // id == (G*64+kh)*64+L
        #pragma unroll
        for (int j = 0; j < 8; ++j) {
            float a = src[j];
            _Float16 h = (_Float16)a;
            _Float16 m = (_Float16)(a - (float)h);
            dst[j] = h;
            dst[j + kFragLvl] = m;
        }
    } else {
        // --- mel basis -> 16x16x32 A-fragments, f16, K padded 513->544 ---
        int id = (bid - kYJobTotal - kFragBlks) * 256 + tid;
        if (id >= 8 * 17 * 64) return;
        int f = id / 1088;
        int rem = id - f * 1088;
        int ks = rem >> 6;
        int L = rem & 63;
        int m = 16 * f + (L & 15);
        int kb = 32 * ks + (L >> 4) * 8;
        _Float16* dst = melfr + (size_t)id * 8;
        #pragma unroll
        for (int j = 0; j < 8; ++j) {
            int k = kb + j;
            dst[j] = (k < 513) ? (_Float16)melb[(size_t)m * 513 + k] : (_Float16)0.0f;
        }
    }
}

// ---- main: 3-term split-f16 32x32x16 MFMA STFT + power, pipelined, 8 waves ----
// block: (nt, g, b). rows {64g..64g+63} U {512+64g..}; N = 256 frames.
// wave tile M=128 x N=32. power[b][t(1024)][bin(544 pad)] f16.
__global__ __launch_bounds__(512, 4)
void stft_power(const _Float16* __restrict__ frags,
                const _Float16* __restrict__ ypad,
                _Float16* __restrict__ pw) {
    __shared__ __align__(16) _Float16 ash[2][16 * 512];   // dbuf x 16 frags x 1KB
    const int tid  = threadIdx.x;
    const int w    = tid >> 6;                            // 0..7
    const int lane = tid & 63;
    const int hi   = lane >> 5;
    const int l32  = lane & 31;
    const int nt = blockIdx.x, g = blockIdx.y, b = blockIdx.z;
    const int t0 = nt * 256 + w * 32;
    const _Float16* yb0 = ypad + (size_t)b * kYPad;
    const _Float16* yb1 = yb0 + kYLvl;

    f32x16 acc[4] = {};

    // slot layout (16 slots/buf): slot = lv*8 + kh2*4 + mf
    auto stageA = [&](int ks, int pbuf) {
        #pragma unroll
        for (int c = 0; c < 2; ++c) {
            int slot = w + 8 * c;
            int lv = slot >> 3, kh2 = (slot >> 2) & 1, mf = slot & 3;
            int G = (mf < 2) ? (2 * g + mf) : (16 + 2 * g + (mf - 2));
            int kh = 2 * ks + kh2;
            const _Float16* gp = frags + (size_t)lv * kFragLvl
                               + ((size_t)(G * 64 + kh) * 64 + lane) * 8;
            __builtin_amdgcn_global_load_lds(
                (const __attribute__((address_space(1))) void*)gp,
                (__attribute__((address_space(3))) void*)&ash[pbuf][slot * 512],
                16, 0, 0);
        }
    };
    // B[k][n]: n = lane&31 (frame), k = 16kh + (lane>>5)*8 + j
    auto loadB = [&](int ks, half8* bh, half8* bm) {
        #pragma unroll
        for (int kh2 = 0; kh2 < 2; ++kh2) {
            int off = (t0 + l32) * kHop + 16 * (2 * ks + kh2) + hi * 8;
            bh[kh2] = *(const half8*)(yb0 + off);
            bm[kh2] = *(const half8*)(yb1 + off);
        }
    };
    auto compute = [&](int pbuf, half8* bh, half8* bm) {
        #pragma unroll
        for (int kh2 = 0; kh2 < 2; ++kh2) {
            #pragma unroll
            for (int mf = 0; mf < 4; ++mf) {
                half8 afh = *(const half8*)&ash[pbuf][(kh2 * 4 + mf) * 512 + lane * 8];
                half8 afm = *(const half8*)&ash[pbuf][(8 + kh2 * 4 + mf) * 512 + lane * 8];
                f32x16 a = acc[mf];
                a = __builtin_amdgcn_mfma_f32_32x32x16_f16(afh, bh[kh2], a, 0, 0, 0);
                a = __builtin_amdgcn_mfma_f32_32x32x16_f16(afm, bh[kh2], a, 0, 0, 0);
                a = __builtin_amdgcn_mfma_f32_32x32x16_f16(afh, bm[kh2], a, 0, 0, 0);
                acc[mf] = a;
            }
        }
    };

    half8 bhA[2], bmA[2], bhB[2], bmB[2];
    stageA(0, 0);
    loadB(0, bhA, bmA);
    for (int kss = 0; kss < 16; ++kss) {
        int ks = 2 * kss;
        __syncthreads();                 // buf0(ks) staged
        stageA(ks + 1, 1);               // async prefetch into other buffer
        loadB(ks + 1, bhB, bmB);         // register prefetch
        compute(0, bhA, bmA);
        __syncthreads();
        if (ks + 2 < 32) {
            stageA(ks + 2, 0);
            loadB(ks + 2, bhA, bmA);
        }
        compute(1, bhB, bmB);
    }

    // epilogue: power = cos^2 + sin^2; acc[mf] (cos) pairs with acc[mf+2] (sin)
    // C/D: col = lane&31, row = (reg&3) + 8*(reg>>2) + 4*(lane>>5)
    const int t = t0 + l32;
    const size_t row = ((size_t)((b << 10) + t)) * kPStride;
    #pragma unroll
    for (int mf = 0; mf < 2; ++mf) {
        #pragma unroll
        for (int q = 0; q < 4; ++q) {
            int binbase = 64 * g + 32 * mf + 8 * q + 4 * hi;
            struct alignas(8) h4 { _Float16 v[4]; } pp;
            #pragma unroll
            for (int r2 = 0; r2 < 4; ++r2) {
                int r = 4 * q + r2;
                float pA = acc[mf][r];
                float pB = acc[mf + 2][r];
                float p2 = pA * pA + pB * pB;
                if (g == 0 && mf == 0 && q == 0 && hi == 0 && r2 == 0) {
                    // packed row 0 = cos bin 0 (sin==0); paired row 512 = cos bin 512
                    p2 = pA * pA;
                    pw[row + 512] = (_Float16)(pB * pB);
                }
                pp.v[r2] = (_Float16)p2;
            }
            *(decltype(pp)*)&pw[row + binbase] = pp;
        }
    }
}

// ---- mel + log via 16x16x32 MFMA: out[b][m][t] = (log(mel+1e-5)+4.5)/5 ----
// block: (nt, b), 4 waves, wave covers 16 frames; M=128 mels, K=544.
__global__ __launch_bounds__(256)
void mel_mfma(const _Float16* __restrict__ melfr, const _Float16* __restrict__ pw,
              float* __restrict__ out) {
    const int tid  = threadIdx.x;
    const int w    = tid >> 6;
    const int lane = tid & 63;
    const int quad = lane >> 4;
    const int l16  = lane & 15;
    const int nt = blockIdx.x, b = blockIdx.y;
    const int t = nt * 64 + w * 16 + l16;

    f32x4 acc[8] = {};
    const _Float16* prow = pw + ((size_t)((b << 10) + t)) * kPStride;
    for (int ks = 0; ks < 17; ++ks) {
        half8 bp = *(const half8*)(prow + 32 * ks + quad * 8);
        #pragma unroll
        for (int f = 0; f < 8; ++f) {
            half8 af = *(const half8*)(melfr + ((size_t)(f * 17 + ks) * 64 + lane) * 8);
            acc[f] = __builtin_amdgcn_mfma_f32_16x16x32_f16(af, bp, acc[f], 0, 0, 0);
        }
    }
    if (t < kFrames) {
        #pragma unroll
        for (int f = 0; f < 8; ++f) {
            #pragma unroll
            for (int r = 0; r < 4; ++r) {
                int m = 16 * f + 4 * quad + r;
                out[((size_t)(b * kMels + m)) * kFrames + t] =
                    (__logf(acc[f][r] + 1e-5f) + 4.5f) * 0.2f;
            }
        }
    }
}

extern "C" void kernel_launch(void* const* d_in, const int* in_sizes, int n_in,
                              void* d_out, int out_size, void* d_ws, size_t ws_size,
                              hipStream_t stream) {
    const float* x     = (const float*)d_in[0];
    const float* basis = (const float*)d_in[1];
    const float* melb  = (const float*)d_in[2];
    float* out = (float*)d_out;

    _Float16* ws    = (_Float16*)d_ws;
    _Float16* frags = ws + kFragOff;
    _Float16* melfr = ws + kMelFrOff;
    _Float16* pw    = ws + kPowOff;

    prep_all<<<dim3(kPrepGrid), 256, 0, stream>>>(x, basis, melb, ws);
    stft_power<<<dim3(4, 8, kBatch), 512, 0, stream>>>(frags, ws, pw);
    mel_mfma<<<dim3(16, kBatch), 256, 0, stream>>>(melfr, pw, out);
}

// Round 7
// 297.932 us; speedup vs baseline: 1.0864x; 1.0864x over previous
//
#include <hip/hip_runtime.h>
#include <math.h>

typedef _Float16 half8 __attribute__((ext_vector_type(8)));
typedef float f32x4 __attribute__((ext_vector_type(4)));

constexpr int kNFFT    = 1024;
constexpr int kHop     = 320;
constexpr int kMels    = 128;
constexpr int kFrames  = 1000;
constexpr int kBatch   = 32;
constexpr int kXLen    = 320000;
constexpr int kYLen    = kXLen - 1;          // 319999
constexpr int kYPad    = 328704;             // >= 1023*320+1024, mult of 2048
constexpr int kYOff    = 512;                // center-pad offset
constexpr float kPre   = 0.97f;
constexpr int kPStride = 544;                // power row stride (bins padded 513->544)

// ws layout (offsets in _Float16 elements)
constexpr size_t kYLvl     = (size_t)kBatch * kYPad;            // halfs per level
constexpr size_t kFragLvl  = 64ull * 32 * 64 * 8;               // 1,048,576 halfs per level
constexpr size_t kFragOff  = 2 * kYLvl;                         // 21,037,056
constexpr size_t kMelFrOff = kFragOff + 2 * kFragLvl;           // 23,134,208
constexpr size_t kMelFrSz  = 8ull * 17 * 64 * 8;                // 69,632 halfs
constexpr size_t kPowOff   = kMelFrOff + kMelFrSz;              // 23,203,840

// fused prep grid partition
constexpr int kYJobBlks   = (kYPad / 8 + 255) / 256;            // 161
constexpr int kYJobTotal  = kYJobBlks * kBatch;                 // 5152
constexpr int kFragBlks   = 131072 / 256;                       // 512
constexpr int kMelBlks    = (8 * 17 * 64) / 256;                // 34
constexpr int kPrepGrid   = kYJobTotal + kFragBlks + kMelBlks;  // 5698

// ---- fused prep: y split / fourier frags (16x16 layout) / mel frags ----
__global__ void prep_all(const float* __restrict__ x, const float* __restrict__ basis,
                         const float* __restrict__ melb, _Float16* __restrict__ ws) {
    _Float16* ypad  = ws;
    _Float16* fr    = ws + kFragOff;
    _Float16* melfr = ws + kMelFrOff;
    const int bid = blockIdx.x;
    const int tid = threadIdx.x;

    if (bid < kYJobTotal) {
        // --- pre-emphasis + center pad, 2-level f16 split, 8 elems/thread ---
        int b = bid / kYJobBlks;
        int blk = bid - b * kYJobBlks;
        int e0 = (blk * 256 + tid) * 8;
        if (e0 >= kYPad) return;
        const float* xb = x + (size_t)b * kXLen;
        int yi = e0 - kYOff;
        float v[8];
        if (yi >= 0 && yi <= kXLen - 9) {
            float4 A = *(const float4*)(xb + yi);
            float4 B = *(const float4*)(xb + yi + 4);
            float C = xb[yi + 8];
            v[0] = A.y - kPre * A.x;  v[1] = A.z - kPre * A.y;
            v[2] = A.w - kPre * A.z;  v[3] = B.x - kPre * A.w;
            v[4] = B.y - kPre * B.x;  v[5] = B.z - kPre * B.y;
            v[6] = B.w - kPre * B.z;  v[7] = C   - kPre * B.w;
        } else {
            #pragma unroll
            for (int j = 0; j < 8; ++j) {
                int g = yi + j;
                v[j] = (g >= 0 && g < kYLen) ? xb[g + 1] - kPre * xb[g] : 0.0f;
            }
        }
        half8 hv, mv;
        #pragma unroll
        for (int j = 0; j < 8; ++j) {
            _Float16 h = (_Float16)v[j];
            hv[j] = h;
            mv[j] = (_Float16)(v[j] - (float)h);
        }
        size_t idx = (size_t)b * kYPad + e0;
        *(half8*)(ypad + idx) = hv;
        *(half8*)(ypad + idx + kYLvl) = mv;
    } else if (bid < kYJobTotal + kFragBlks) {
        // --- fourier basis -> 16x16x32 A-fragments, 2-level f16 split ---
        // packed rows: 0..512 cos bins 0..512; 513..1023 sin bins 1..511 (orig r+1)
        // frag[lv][g][ks][lane][j]: A[m=16g+(lane&15)][k=32ks+(lane>>4)*8+j]
        int id = (bid - kYJobTotal) * 256 + tid;   // < 131072
        int L  = id & 63;
        int ks = (id >> 6) & 31;
        int g  = id >> 11;                          // 0..63
        int r  = 16 * g + (L & 15);
        int orig = (r <= 512) ? r : r + 1;
        const float* src = basis + (size_t)orig * kNFFT + 32 * ks + (L >> 4) * 8;
        _Float16* dst = fr + (size_t)id * 8;        // id == (g*32+ks)*64+L
        #pragma unroll
        for (int j = 0; j < 8; ++j) {
            float a = src[j];
            _Float16 h = (_Float16)a;
            _Float16 m = (_Float16)(a - (float)h);
            dst[j] = h;
            dst[j + kFragLvl] = m;
        }
    } else {
        // --- mel basis -> 16x16x32 A-fragments, f16, K padded 513->544 ---
        int id = (bid - kYJobTotal - kFragBlks) * 256 + tid;
        if (id >= 8 * 17 * 64) return;
        int f = id / 1088;
        int rem = id - f * 1088;
        int ks = rem >> 6;
        int L = rem & 63;
        int m = 16 * f + (L & 15);
        int kb = 32 * ks + (L >> 4) * 8;
        _Float16* dst = melfr + (size_t)id * 8;
        #pragma unroll
        for (int j = 0; j < 8; ++j) {
            int k = kb + j;
            dst[j] = (k < 513) ? (_Float16)melb[(size_t)m * 513 + k] : (_Float16)0.0f;
        }
    }
}

// ---- main: 3-term split-f16 MFMA STFT + power, pipelined, 8 waves ----
// 1-D grid, XCD-pinned swizzle: the 8 g-blocks of one (b,nt) pair get
// consecutive linear ids with identical (lin % 8) -> same XCD -> y slice
// is fetched into that XCD's L2 once and reused 8x.
// wave tile M=128 x N=32. power[b][t(1024)][bin(544 pad)] f16.
__global__ __launch_bounds__(512, 4)
void stft_power(const _Float16* __restrict__ frags,
                const _Float16* __restrict__ ypad,
                _Float16* __restrict__ pw) {
    __shared__ __align__(16) _Float16 ash[2][16 * 512];   // dbuf x 16 frags x 1KB
    const int tid  = threadIdx.x;
    const int w    = tid >> 6;                            // 0..7
    const int lane = tid & 63;
    const int quad = lane >> 4;
    const int l16  = lane & 15;

    // swizzle: lin = ((s*8 + g) * 8) + r ; pair (b,nt) = r*16+s pinned to XCD r
    const int lin = blockIdx.x;
    const int r_  = lin & 7;
    const int j_  = lin >> 3;
    const int g   = j_ & 7;
    const int s_  = j_ >> 3;                              // 0..15
    const int pair = r_ * 16 + s_;                        // 0..127
    const int b   = pair >> 2;
    const int nt  = pair & 3;

    const int t0 = nt * 256 + w * 32;
    const _Float16* yb0 = ypad + (size_t)b * kYPad;
    const _Float16* yb1 = yb0 + kYLvl;

    f32x4 acc[8][2] = {};

    auto stageA = [&](int ks, int pbuf) {
        #pragma unroll
        for (int c = 0; c < 2; ++c) {
            int slot = w + 8 * c;                 // wave w stages frag f=w, both levels
            int f = slot & 7, lv = slot >> 3;
            int Gf = (f < 4) ? (4 * g + f) : (32 + 4 * g + (f - 4));
            const _Float16* gp = frags + (size_t)lv * kFragLvl
                               + ((size_t)(Gf * 32 + ks) * 64 + lane) * 8;
            __builtin_amdgcn_global_load_lds(
                (const __attribute__((address_space(1))) void*)gp,
                (__attribute__((address_space(3))) void*)&ash[pbuf][slot * 512],
                16, 0, 0);
        }
    };
    auto loadB = [&](int ks, half8* bh, half8* bm) {
        #pragma unroll
        for (int nf = 0; nf < 2; ++nf) {
            int off = (t0 + nf * 16 + l16) * kHop + ks * 32 + quad * 8;
            bh[nf] = *(const half8*)(yb0 + off);
            bm[nf] = *(const half8*)(yb1 + off);
        }
    };
    auto compute = [&](int pbuf, half8* bh, half8* bm) {
        #pragma unroll
        for (int f = 0; f < 8; ++f) {
            half8 afh = *(const half8*)&ash[pbuf][f * 512 + lane * 8];
            half8 afm = *(const half8*)&ash[pbuf][(8 + f) * 512 + lane * 8];
            #pragma unroll
            for (int nf = 0; nf < 2; ++nf) {
                f32x4 a = acc[f][nf];
                a = __builtin_amdgcn_mfma_f32_16x16x32_f16(afh, bh[nf], a, 0, 0, 0);
                a = __builtin_amdgcn_mfma_f32_16x16x32_f16(afm, bh[nf], a, 0, 0, 0);
                a = __builtin_amdgcn_mfma_f32_16x16x32_f16(afh, bm[nf], a, 0, 0, 0);
                acc[f][nf] = a;
            }
        }
    };

    half8 bhA[2], bmA[2], bhB[2], bmB[2];
    stageA(0, 0);
    loadB(0, bhA, bmA);
    for (int kss = 0; kss < 16; ++kss) {
        int ks = 2 * kss;
        __syncthreads();                 // buf0(ks) staged (drained at this barrier)
        stageA(ks + 1, 1);               // async prefetch into other buffer
        loadB(ks + 1, bhB, bmB);         // register prefetch
        compute(0, bhA, bmA);
        __syncthreads();
        if (ks + 2 < 32) {
            stageA(ks + 2, 0);
            loadB(ks + 2, bhA, bmA);
        }
        compute(1, bhB, bmB);
    }

    // epilogue: power = cos^2 + sin^2; chunk f (cos) pairs with f+4 (sin, same bin)
    #pragma unroll
    for (int mf = 0; mf < 4; ++mf) {
        int b0 = 64 * g + 16 * mf + 4 * quad;
        #pragma unroll
        for (int nf = 0; nf < 2; ++nf) {
            int t = t0 + nf * 16 + l16;
            size_t row = ((size_t)((b << 10) + t)) * kPStride;
            struct alignas(8) h4 { _Float16 v[4]; } pp;
            #pragma unroll
            for (int rr = 0; rr < 4; ++rr) {
                float pA = acc[mf][nf][rr];
                float pB = acc[4 + mf][nf][rr];
                float p2 = pA * pA + pB * pB;
                if (g == 0 && mf == 0 && quad == 0 && rr == 0) {
                    // packed row 0 = cos bin 0 (sin==0); paired row 512 = cos bin 512
                    p2 = pA * pA;
                    pw[row + 512] = (_Float16)(pB * pB);
                }
                pp.v[rr] = (_Float16)p2;
            }
            *(decltype(pp)*)&pw[row + b0] = pp;
        }
    }
}

// ---- mel + log via MFMA: out[b][m][t] = (log(mel+1e-5)+4.5)/5 ----
// block: (nt, b), 4 waves, wave covers 32 frames; M=128 mels, K=544.
__global__ __launch_bounds__(256)
void mel_mfma(const _Float16* __restrict__ melfr, const _Float16* __restrict__ pw,
              float* __restrict__ out) {
    const int tid  = threadIdx.x;
    const int w    = tid >> 6;
    const int lane = tid & 63;
    const int quad = lane >> 4;
    const int l16  = lane & 15;
    const int nt = blockIdx.x, b = blockIdx.y;
    const int t0 = nt * 128 + w * 32;

    f32x4 acc[8][2] = {};
    for (int ks = 0; ks < 17; ++ks) {
        half8 bp[2];
        #pragma unroll
        for (int nf = 0; nf < 2; ++nf) {
            int t = t0 + nf * 16 + l16;
            bp[nf] = *(const half8*)(pw + ((size_t)((b << 10) + t)) * kPStride
                                     + 32 * ks + quad * 8);
        }
        #pragma unroll
        for (int f = 0; f < 8; ++f) {
            half8 af = *(const half8*)(melfr + ((size_t)(f * 17 + ks) * 64 + lane) * 8);
            #pragma unroll
            for (int nf = 0; nf < 2; ++nf)
                acc[f][nf] = __builtin_amdgcn_mfma_f32_16x16x32_f16(af, bp[nf], acc[f][nf], 0, 0, 0);
        }
    }
    #pragma unroll
    for (int f = 0; f < 8; ++f) {
        #pragma unroll
        for (int nf = 0; nf < 2; ++nf) {
            int t = t0 + nf * 16 + l16;
            if (t < kFrames) {
                #pragma unroll
                for (int r = 0; r < 4; ++r) {
                    int m = 16 * f + 4 * quad + r;
                    out[((size_t)(b * kMels + m)) * kFrames + t] =
                        (__logf(acc[f][nf][r] + 1e-5f) + 4.5f) * 0.2f;
                }
            }
        }
    }
}

extern "C" void kernel_launch(void* const* d_in, const int* in_sizes, int n_in,
                              void* d_out, int out_size, void* d_ws, size_t ws_size,
                              hipStream_t stream) {
    const float* x     = (const float*)d_in[0];
    const float* basis = (const float*)d_in[1];
    const float* melb  = (const float*)d_in[2];
    float* out = (float*)d_out;

    _Float16* ws    = (_Float16*)d_ws;
    _Float16* frags = ws + kFragOff;
    _Float16* melfr = ws + kMelFrOff;
    _Float16* pw    = ws + kPowOff;

    prep_all<<<dim3(kPrepGrid), 256, 0, stream>>>(x, basis, melb, ws);
    stft_power<<<dim3(1024), 512, 0, stream>>>(frags, ws, pw);
    mel_mfma<<<dim3(8, kBatch), 256, 0, stream>>>(melfr, pw, out);
}

// Round 8
// 265.091 us; speedup vs baseline: 1.2210x; 1.1239x over previous
//
#include <hip/hip_runtime.h>
#include <math.h>

typedef _Float16 half8 __attribute__((ext_vector_type(8)));
typedef float f32x4 __attribute__((ext_vector_type(4)));

constexpr int kNFFT    = 1024;
constexpr int kHop     = 320;
constexpr int kMels    = 128;
constexpr int kFrames  = 1000;
constexpr int kBatch   = 32;
constexpr int kXLen    = 320000;
constexpr int kYLen    = kXLen - 1;          // 319999
constexpr int kYPad    = 328704;             // >= 1023*320+1024, mult of 2048
constexpr int kYOff    = 512;                // center-pad offset
constexpr float kPre   = 0.97f;
constexpr int kPStride = 544;                // power row stride (bins padded 513->544)
// Hann support: basis columns 112..911 nonzero -> k-steps 3..28 only
constexpr int kKsLo    = 3;
constexpr int kKsHi    = 28;                 // inclusive; 26 steps

// ws layout (offsets in _Float16 elements)
constexpr size_t kYLvl     = (size_t)kBatch * kYPad;            // halfs per level
constexpr size_t kFragLvl  = 64ull * 32 * 64 * 8;               // 1,048,576 halfs per level
constexpr size_t kFragOff  = 2 * kYLvl;                         // 21,037,056
constexpr size_t kMelFrOff = kFragOff + 2 * kFragLvl;           // 23,134,208
constexpr size_t kMelFrSz  = 8ull * 17 * 64 * 8;                // 69,632 halfs
constexpr size_t kPowOff   = kMelFrOff + kMelFrSz;              // 23,203,840

// fused prep grid partition
constexpr int kYJobBlks   = (kYPad / 8 + 255) / 256;            // 161
constexpr int kYJobTotal  = kYJobBlks * kBatch;                 // 5152
constexpr int kFragBlks   = 131072 / 256;                       // 512
constexpr int kMelBlks    = (8 * 17 * 64) / 256;                // 34
constexpr int kPrepGrid   = kYJobTotal + kFragBlks + kMelBlks;  // 5698

// ---- fused prep: y split / fourier frags (16x16 layout) / mel frags ----
__global__ void prep_all(const float* __restrict__ x, const float* __restrict__ basis,
                         const float* __restrict__ melb, _Float16* __restrict__ ws) {
    _Float16* ypad  = ws;
    _Float16* fr    = ws + kFragOff;
    _Float16* melfr = ws + kMelFrOff;
    const int bid = blockIdx.x;
    const int tid = threadIdx.x;

    if (bid < kYJobTotal) {
        // --- pre-emphasis + center pad, 2-level f16 split, 8 elems/thread ---
        int b = bid / kYJobBlks;
        int blk = bid - b * kYJobBlks;
        int e0 = (blk * 256 + tid) * 8;
        if (e0 >= kYPad) return;
        const float* xb = x + (size_t)b * kXLen;
        int yi = e0 - kYOff;
        float v[8];
        if (yi >= 0 && yi <= kXLen - 9) {
            float4 A = *(const float4*)(xb + yi);
            float4 B = *(const float4*)(xb + yi + 4);
            float C = xb[yi + 8];
            v[0] = A.y - kPre * A.x;  v[1] = A.z - kPre * A.y;
            v[2] = A.w - kPre * A.z;  v[3] = B.x - kPre * A.w;
            v[4] = B.y - kPre * B.x;  v[5] = B.z - kPre * B.y;
            v[6] = B.w - kPre * B.z;  v[7] = C   - kPre * B.w;
        } else {
            #pragma unroll
            for (int j = 0; j < 8; ++j) {
                int g = yi + j;
                v[j] = (g >= 0 && g < kYLen) ? xb[g + 1] - kPre * xb[g] : 0.0f;
            }
        }
        half8 hv, mv;
        #pragma unroll
        for (int j = 0; j < 8; ++j) {
            _Float16 h = (_Float16)v[j];
            hv[j] = h;
            mv[j] = (_Float16)(v[j] - (float)h);
        }
        size_t idx = (size_t)b * kYPad + e0;
        *(half8*)(ypad + idx) = hv;
        *(half8*)(ypad + idx + kYLvl) = mv;
    } else if (bid < kYJobTotal + kFragBlks) {
        // --- fourier basis -> 16x16x32 A-fragments, 2-level f16 split ---
        // packed rows: 0..512 cos bins 0..512; 513..1023 sin bins 1..511 (orig r+1)
        // frag[lv][g][ks][lane][j]: A[m=16g+(lane&15)][k=32ks+(lane>>4)*8+j]
        int id = (bid - kYJobTotal) * 256 + tid;   // < 131072
        int L  = id & 63;
        int ks = (id >> 6) & 31;
        int g  = id >> 11;                          // 0..63
        int r  = 16 * g + (L & 15);
        int orig = (r <= 512) ? r : r + 1;
        const float* src = basis + (size_t)orig * kNFFT + 32 * ks + (L >> 4) * 8;
        _Float16* dst = fr + (size_t)id * 8;        // id == (g*32+ks)*64+L
        #pragma unroll
        for (int j = 0; j < 8; ++j) {
            float a = src[j];
            _Float16 h = (_Float16)a;
            _Float16 m = (_Float16)(a - (float)h);
            dst[j] = h;
            dst[j + kFragLvl] = m;
        }
    } else {
        // --- mel basis -> 16x16x32 A-fragments, f16, K padded 513->544 ---
        int id = (bid - kYJobTotal - kFragBlks) * 256 + tid;
        if (id >= 8 * 17 * 64) return;
        int f = id / 1088;
        int rem = id - f * 1088;
        int ks = rem >> 6;
        int L = rem & 63;
        int m = 16 * f + (L & 15);
        int kb = 32 * ks + (L >> 4) * 8;
        _Float16* dst = melfr + (size_t)id * 8;
        #pragma unroll
        for (int j = 0; j < 8; ++j) {
            int k = kb + j;
            dst[j] = (k < 513) ? (_Float16)melb[(size_t)m * 513 + k] : (_Float16)0.0f;
        }
    }
}

// ---- main: 3-term split-f16 MFMA STFT + power, pipelined, 8 waves ----
// block: (nt, g, b). rows {64g..64g+63} U {512+64g..}; block N = 512 frames.
// wave tile M=128 x N=64 (nf=4). k-steps 3..28 only (window support).
// power[b][t(1024)][bin(544 pad)] f16.
__global__ __launch_bounds__(512, 2)
void stft_power(const _Float16* __restrict__ frags,
                const _Float16* __restrict__ ypad,
                _Float16* __restrict__ pw) {
    __shared__ __align__(16) _Float16 ash[2][16 * 512];   // dbuf x 16 frags x 1KB
    const int tid  = threadIdx.x;
    const int w    = tid >> 6;                            // 0..7
    const int lane = tid & 63;
    const int quad = lane >> 4;
    const int l16  = lane & 15;
    const int nt = blockIdx.x, g = blockIdx.y, b = blockIdx.z;
    const int t0 = nt * 512 + w * 64;
    const _Float16* yb0 = ypad + (size_t)b * kYPad;
    const _Float16* yb1 = yb0 + kYLvl;

    f32x4 acc[8][4] = {};

    auto stageA = [&](int ks, int pbuf) {
        #pragma unroll
        for (int c = 0; c < 2; ++c) {
            int slot = w + 8 * c;                 // wave w stages frag f=w, both levels
            int f = slot & 7, lv = slot >> 3;
            int Gf = (f < 4) ? (4 * g + f) : (32 + 4 * g + (f - 4));
            const _Float16* gp = frags + (size_t)lv * kFragLvl
                               + ((size_t)(Gf * 32 + ks) * 64 + lane) * 8;
            __builtin_amdgcn_global_load_lds(
                (const __attribute__((address_space(1))) void*)gp,
                (__attribute__((address_space(3))) void*)&ash[pbuf][slot * 512],
                16, 0, 0);
        }
    };
    auto loadB = [&](int ks, half8* bh, half8* bm) {
        #pragma unroll
        for (int nf = 0; nf < 4; ++nf) {
            int off = (t0 + nf * 16 + l16) * kHop + ks * 32 + quad * 8;
            bh[nf] = *(const half8*)(yb0 + off);
            bm[nf] = *(const half8*)(yb1 + off);
        }
    };
    auto compute = [&](int pbuf, half8* bh, half8* bm) {
        #pragma unroll
        for (int f = 0; f < 8; ++f) {
            half8 afh = *(const half8*)&ash[pbuf][f * 512 + lane * 8];
            half8 afm = *(const half8*)&ash[pbuf][(8 + f) * 512 + lane * 8];
            #pragma unroll
            for (int nf = 0; nf < 4; ++nf) {
                f32x4 a = acc[f][nf];
                a = __builtin_amdgcn_mfma_f32_16x16x32_f16(afh, bh[nf], a, 0, 0, 0);
                a = __builtin_amdgcn_mfma_f32_16x16x32_f16(afm, bh[nf], a, 0, 0, 0);
                a = __builtin_amdgcn_mfma_f32_16x16x32_f16(afh, bm[nf], a, 0, 0, 0);
                acc[f][nf] = a;
            }
        }
    };

    half8 bhA[4], bmA[4], bhB[4], bmB[4];
    stageA(kKsLo, 0);
    loadB(kKsLo, bhA, bmA);
    for (int kss = 0; kss < 13; ++kss) {
        int ks = kKsLo + 2 * kss;
        __syncthreads();                 // buf0(ks) staged (drained at this barrier)
        stageA(ks + 1, 1);               // async prefetch into other buffer
        loadB(ks + 1, bhB, bmB);         // register prefetch
        compute(0, bhA, bmA);
        __syncthreads();
        if (ks + 2 <= kKsHi) {
            stageA(ks + 2, 0);
            loadB(ks + 2, bhA, bmA);
        }
        compute(1, bhB, bmB);
    }

    // epilogue: power = cos^2 + sin^2; chunk f (cos) pairs with f+4 (sin, same bin)
    #pragma unroll
    for (int mf = 0; mf < 4; ++mf) {
        int b0 = 64 * g + 16 * mf + 4 * quad;
        #pragma unroll
        for (int nf = 0; nf < 4; ++nf) {
            int t = t0 + nf * 16 + l16;
            size_t row = ((size_t)((b << 10) + t)) * kPStride;
            struct alignas(8) h4 { _Float16 v[4]; } pp;
            #pragma unroll
            for (int rr = 0; rr < 4; ++rr) {
                float pA = acc[mf][nf][rr];
                float pB = acc[4 + mf][nf][rr];
                float p2 = pA * pA + pB * pB;
                if (g == 0 && mf == 0 && quad == 0 && rr == 0) {
                    // packed row 0 = cos bin 0 (sin==0); paired row 512 = cos bin 512
                    p2 = pA * pA;
                    pw[row + 512] = (_Float16)(pB * pB);
                }
                pp.v[rr] = (_Float16)p2;
            }
            *(decltype(pp)*)&pw[row + b0] = pp;
        }
    }
}

// ---- mel + log via MFMA: out[b][m][t] = (log(mel+1e-5)+4.5)/5 ----
// block: (nt, b), 4 waves, wave covers 32 frames; M=128 mels, K=544.
__global__ __launch_bounds__(256)
void mel_mfma(const _Float16* __restrict__ melfr, const _Float16* __restrict__ pw,
              float* __restrict__ out) {
    const int tid  = threadIdx.x;
    const int w    = tid >> 6;
    const int lane = tid & 63;
    const int quad = lane >> 4;
    const int l16  = lane & 15;
    const int nt = blockIdx.x, b = blockIdx.y;
    const int t0 = nt * 128 + w * 32;

    f32x4 acc[8][2] = {};
    for (int ks = 0; ks < 17; ++ks) {
        half8 bp[2];
        #pragma unroll
        for (int nf = 0; nf < 2; ++nf) {
            int t = t0 + nf * 16 + l16;
            bp[nf] = *(const half8*)(pw + ((size_t)((b << 10) + t)) * kPStride
                                     + 32 * ks + quad * 8);
        }
        #pragma unroll
        for (int f = 0; f < 8; ++f) {
            half8 af = *(const half8*)(melfr + ((size_t)(f * 17 + ks) * 64 + lane) * 8);
            #pragma unroll
            for (int nf = 0; nf < 2; ++nf)
                acc[f][nf] = __builtin_amdgcn_mfma_f32_16x16x32_f16(af, bp[nf], acc[f][nf], 0, 0, 0);
        }
    }
    #pragma unroll
    for (int f = 0; f < 8; ++f) {
        #pragma unroll
        for (int nf = 0; nf < 2; ++nf) {
            int t = t0 + nf * 16 + l16;
            if (t < kFrames) {
                #pragma unroll
                for (int r = 0; r < 4; ++r) {
                    int m = 16 * f + 4 * quad + r;
                    out[((size_t)(b * kMels + m)) * kFrames + t] =
                        (__logf(acc[f][nf][r] + 1e-5f) + 4.5f) * 0.2f;
                }
            }
        }
    }
}

extern "C" void kernel_launch(void* const* d_in, const int* in_sizes, int n_in,
                              void* d_out, int out_size, void* d_ws, size_t ws_size,
                              hipStream_t stream) {
    const float* x     = (const float*)d_in[0];
    const float* basis = (const float*)d_in[1];
    const float* melb  = (const float*)d_in[2];
    float* out = (float*)d_out;

    _Float16* ws    = (_Float16*)d_ws;
    _Float16* frags = ws + kFragOff;
    _Float16* melfr = ws + kMelFrOff;
    _Float16* pw    = ws + kPowOff;

    prep_all<<<dim3(kPrepGrid), 256, 0, stream>>>(x, basis, melb, ws);
    stft_power<<<dim3(2, 8, kBatch), 512, 0, stream>>>(frags, ws, pw);
    mel_mfma<<<dim3(8, kBatch), 256, 0, stream>>>(melfr, pw, out);
}